// Round 7
// baseline (550.193 us; speedup 1.0000x reference)
//
#include <hip/hip_runtime.h>
#include <hip/hip_bf16.h>

#define NTOT 8192
#define DDIM 256
#define ROWS 32                 // rows per attn block
#define NXCD 8                  // j-slices (== XCDs); js = blockIdx.x & 7
#define JSLICE (NTOT / NXCD)    // 1024 j per slice
#define JWAVE (JSLICE / 4)      // 256 j per wave (jg = 0..3)
#define NITER (JWAVE / 32)      // 8 j-tiles per wave
#define NTSTR 131584            // hTf nt-stride in elems: 257*64*8
#define HTF_ELEMS (16 * NTSTR)

typedef __attribute__((ext_vector_type(8))) short short8;
typedef __attribute__((ext_vector_type(4))) float floatx4;
typedef __attribute__((ext_vector_type(4))) int intx4;

static __device__ __forceinline__ short bfp(float f) {
  __hip_bfloat16 b = __float2bfloat16(f);
  return *(short*)&b;
}

// ------- per-row exp tables: rc=(e^s1, e^.01s1), etab=(e^s2, e^.01s2)
// exp(leaky(s1+s2)) = max(e^s1*e^s2, e^.01s1*e^.01s2)
__global__ __launch_bounds__(256) void gat_scores(const float* __restrict__ h,
                                                  const float* __restrict__ a,
                                                  float2* __restrict__ rc,
                                                  float2* __restrict__ etab) {
  int row  = blockIdx.x * 4 + (threadIdx.x >> 6);
  int lane = threadIdx.x & 63;
  const float* hr = h + (size_t)row * DDIM;
  float p1 = 0.f, p2 = 0.f;
#pragma unroll
  for (int k = 0; k < DDIM / 64; ++k) {
    int idx  = lane + 64 * k;
    float hv = hr[idx];
    p1 += hv * a[idx];
    p2 += hv * a[DDIM + idx];
  }
#pragma unroll
  for (int off = 32; off > 0; off >>= 1) {
    p1 += __shfl_down(p1, off, 64);
    p2 += __shfl_down(p2, off, 64);
  }
  if (lane == 0) {
    rc[row]   = make_float2(__expf(p1), __expf(0.01f * p1));
    etab[row] = make_float2(__expf(p2), __expf(0.01f * p2));
  }
}

// ---------------- pack h -> fragment-major bf16 hTf (padded nt-stride) ------
// hTf[((n*257 + jblk)*64 + lane)*8 + i] = H[jblk*32 + (lane>>4)*8 + i][n*16 + (lane&15)]
__global__ __launch_bounds__(256) void gat_hpack(const float* __restrict__ h,
                                                 ushort* __restrict__ hTf) {
  __shared__ float tile[64][257];
  const int t    = threadIdx.x;
  const int lane = t & 63;
  const int w    = t >> 6;
  const int quad = lane >> 4;
  const int c    = lane & 15;
  const int i0   = blockIdx.x * 64;

#pragma unroll
  for (int it = 0; it < 16; ++it) {
    int r = it * 4 + w;
    float4 v = *(const float4*)(h + (size_t)(i0 + r) * DDIM + lane * 4);
    tile[r][lane * 4 + 0] = v.x; tile[r][lane * 4 + 1] = v.y;
    tile[r][lane * 4 + 2] = v.z; tile[r][lane * 4 + 3] = v.w;
  }
  __syncthreads();

#pragma unroll
  for (int k = 0; k < 4; ++k) {
    const int n = 4 * k + w;
#pragma unroll
    for (int jbl = 0; jbl < 2; ++jbl) {
      short8 vv;
#pragma unroll
      for (int i = 0; i < 8; ++i) {
        float f = tile[jbl * 32 + quad * 8 + i][n * 16 + c];
        vv[i] = bfp(f);
      }
      *(short8*)(hTf + ((size_t)(n * 257 + i0 / 32 + jbl) * 64 + lane) * 8) = vv;
    }
  }
}

// ---------------- XCD-affine fused softmax-num + P@h partials via MFMA ------
// grid 2048 x 1024 thr (16 waves). Block bx: js = bx&7 (round-robin -> all
// blocks on XCD k share j-slice k; hTf[js] = 525 KB is L2-RESIDENT), rt=bx>>3.
// Block: rows [32rt,+32) x j [1024js,+1024). Wave (rg=w&1, cg=(w>>1)&1,
// jg=w>>2): rows 16, cols 128, j [256jg,+256). Barrier-free K-loop (R6).
// Writes PARTIAL sums/denoms per js; gat_combine reduces the 8 slices.
__global__ __launch_bounds__(1024, 4) void gat_attn(const ushort* __restrict__ hTf,
                                                    const int* __restrict__ adj,
                                                    const float2* __restrict__ rc,
                                                    const float2* __restrict__ etab,
                                                    float* __restrict__ pout,
                                                    float* __restrict__ plp) {
  __shared__ float slab[8][32][64];   // jg merge buffers: 64 KB
  __shared__ float lsum[4][32];       // per-jg denom partials

  const int t    = threadIdx.x;
  const int lane = t & 63;
  const int w    = t >> 6;
  const int quad = lane >> 4;
  const int c    = lane & 15;
  const int rg   = w & 1;
  const int cg   = (w >> 1) & 1;
  const int jg   = w >> 2;
  const int js   = blockIdx.x & (NXCD - 1);   // j-slice == XCD id (round-robin)
  const int rt   = blockIdx.x >> 3;
  const int r0   = rt * ROWS;
  const int rb   = r0 + rg * 16;      // this wave's 16-row base
  const int j0   = js * JSLICE + jg * JWAVE;

  const float2 rcv = rc[rb + c];
  const float E1 = rcv.x, E2 = rcv.y;

  const int*    ap  = adj + (size_t)(rb + c) * NTOT + j0 + quad * 8;
  const float*  etb = (const float*)(etab + j0 + quad * 8);
  const ushort* hb  = hTf + (size_t)(8 * cg) * NTSTR + (size_t)(j0 / 32) * 512 + lane * 8;

  floatx4 acc[8];
#pragma unroll
  for (int q = 0; q < 8; ++q) acc[q] = (floatx4){0.f, 0.f, 0.f, 0.f};

  float lp = 0.f;
  short8 bA[4], bB[4];
  intx4  aj0, aj1;
  float4 ea, eb, ec, ed;

  #define LDA(jt)                                                              \
    {                                                                          \
      const int* p_ = ap + (size_t)(jt) * 32;                                  \
      aj0 = __builtin_nontemporal_load((const intx4*)p_);                      \
      aj1 = __builtin_nontemporal_load((const intx4*)(p_ + 4));                \
    }
  #define LDE(jt)                                                              \
    {                                                                          \
      const float* e_ = etb + (size_t)(jt) * 64;                               \
      ea = ((const float4*)e_)[0];                                             \
      eb = ((const float4*)e_)[1];                                             \
      ec = ((const float4*)e_)[2];                                             \
      ed = ((const float4*)e_)[3];                                             \
    }
  #define LDBA(jt)                                                             \
    _Pragma("unroll")                                                          \
    for (int q = 0; q < 4; ++q)                                                \
      bA[q] = *(const short8*)(hb + (size_t)(jt) * 512 + (size_t)q * NTSTR);
  #define LDBB(jt)                                                             \
    _Pragma("unroll")                                                          \
    for (int q = 0; q < 4; ++q)                                                \
      bB[q] = *(const short8*)(hb + (size_t)(jt) * 512 + (size_t)(4 + q) * NTSTR);

  // prologue
  LDBA(0)
  LDBB(0)
  LDA(0)
  LDE(0)

  for (int jt = 0; jt < NITER; ++jt) {
    const int jn = (jt + 1) & (NITER - 1);   // wrapped (branch-free)

    // ---- P-build: p = (adj>0) ? max(E1*t1, E2*t2) : 0 ----
    const int   am[8] = {aj0[0], aj0[1], aj0[2], aj0[3], aj1[0], aj1[1], aj1[2], aj1[3]};
    const float tp[16] = {ea.x, ea.y, ea.z, ea.w, eb.x, eb.y, eb.z, eb.w,
                          ec.x, ec.y, ec.z, ec.w, ed.x, ed.y, ed.z, ed.w};
    short8 pa;
#pragma unroll
    for (int i = 0; i < 8; ++i) {
      const float p = (am[i] > 0) ? fmaxf(E1 * tp[2 * i], E2 * tp[2 * i + 1]) : 0.f;
      lp += p;
      pa[i] = bfp(p);
    }

    // ---- prefetch next adj + etab; pin ----
    LDA(jn)
    LDE(jn)
    __builtin_amdgcn_sched_barrier(0);

    // ---- MFMA col-frags 0-3, refill bA, pin ----
#pragma unroll
    for (int q = 0; q < 4; ++q)
      acc[q] = __builtin_amdgcn_mfma_f32_16x16x32_bf16(pa, bA[q], acc[q], 0, 0, 0);
    LDBA(jn)
    __builtin_amdgcn_sched_barrier(0);

    // ---- MFMA col-frags 4-7, refill bB, pin ----
#pragma unroll
    for (int q = 0; q < 4; ++q)
      acc[4 + q] = __builtin_amdgcn_mfma_f32_16x16x32_bf16(pa, bB[q], acc[4 + q], 0, 0, 0);
    LDBB(jn)
    __builtin_amdgcn_sched_barrier(0);
  }
  #undef LDA
  #undef LDE
  #undef LDBA
  #undef LDBB

  // ---- denom: fold quads -> every lane holds row-(rb+c) sum over wave's j ----
  lp += __shfl_xor(lp, 16, 64);
  lp += __shfl_xor(lp, 32, 64);
  if (cg == 0 && lane < 16) lsum[jg][rg * 16 + lane] = lp;

  // ---- jg-tree merge: 4 -> 2 -> 1 ----
  const int sidx = rg * 2 + cg;
  if (jg >= 2) {
#pragma unroll
    for (int q = 0; q < 8; ++q)
#pragma unroll
      for (int r = 0; r < 4; ++r)
        slab[(jg - 2) * 4 + sidx][q * 4 + r][lane] = acc[q][r];
  }
  __syncthreads();
  if (jg < 2) {
#pragma unroll
    for (int q = 0; q < 8; ++q)
#pragma unroll
      for (int r = 0; r < 4; ++r)
        acc[q][r] += slab[jg * 4 + sidx][q * 4 + r][lane];
  }
  __syncthreads();
  if (jg == 1) {
#pragma unroll
    for (int q = 0; q < 8; ++q)
#pragma unroll
      for (int r = 0; r < 4; ++r)
        slab[sidx][q * 4 + r][lane] = acc[q][r];
  }
  __syncthreads();
  if (jg == 0) {
    float* pob = pout + (size_t)js * NTOT * DDIM;
#pragma unroll
    for (int q = 0; q < 8; ++q)
#pragma unroll
      for (int r = 0; r < 4; ++r) {
        float v = acc[q][r] + slab[sidx][q * 4 + r][lane];
        __builtin_nontemporal_store(
            v, &pob[(size_t)(rb + quad * 4 + r) * DDIM + cg * 128 + q * 16 + c]);
      }
    if (cg == 0 && lane < 16) {
      const int lr = rg * 16 + lane;
      plp[(size_t)js * NTOT + r0 + lr] =
          lsum[0][lr] + lsum[1][lr] + lsum[2][lr] + lsum[3][lr];
    }
  }
}

// ---------------- combine the 8 j-slice partials, divide by denom -----------
__global__ __launch_bounds__(256) void gat_combine(const float* __restrict__ pout,
                                                   const float* __restrict__ plp,
                                                   float* __restrict__ out) {
  const int idx = blockIdx.x * 256 + threadIdx.x;   // float4-group index
  const int row = idx >> 6;                          // 64 float4 per row
  float4 s = make_float4(0.f, 0.f, 0.f, 0.f);
  float d = 0.f;
#pragma unroll
  for (int js = 0; js < NXCD; ++js) {
    float4 v = ((const float4*)(pout + (size_t)js * NTOT * DDIM))[idx];
    s.x += v.x; s.y += v.y; s.z += v.z; s.w += v.w;
    d += plp[(size_t)js * NTOT + row];
  }
  const float inv = 1.f / d;
  __builtin_nontemporal_store(s.x * inv, &out[idx * 4 + 0]);
  __builtin_nontemporal_store(s.y * inv, &out[idx * 4 + 1]);
  __builtin_nontemporal_store(s.z * inv, &out[idx * 4 + 2]);
  __builtin_nontemporal_store(s.w * inv, &out[idx * 4 + 3]);
}

extern "C" void kernel_launch(void* const* d_in, const int* in_sizes, int n_in,
                              void* d_out, int out_size, void* d_ws, size_t ws_size,
                              hipStream_t stream) {
  const float* h   = (const float*)d_in[0];
  const int*   adj = (const int*)d_in[1];
  const float* a   = (const float*)d_in[2];
  float* out = (float*)d_out;

  float2*   rc    = (float2*)d_ws;                       // 8192 float2 = 64 KB
  float2*   etab  = rc + NTOT;                           // 8192 float2 = 64 KB
  ushort*   hTf   = (ushort*)(etab + NTOT);              // 4.21 MB bf16
  float*    pout  = (float*)(hTf + HTF_ELEMS);           // 8 x 8192 x 256 f32 = 64 MB
  float*    plp   = pout + (size_t)NXCD * NTOT * DDIM;   // 8 x 8192 f32

  gat_scores<<<NTOT / 4, 256, 0, stream>>>(h, a, rc, etab);
  gat_hpack<<<NTOT / 64, 256, 0, stream>>>(h, hTf);
  gat_attn<<<NXCD * (NTOT / ROWS), 1024, 0, stream>>>(hTf, adj, rc, etab, pout, plp);
  gat_combine<<<(NTOT * DDIM / 4) / 256, 256, 0, stream>>>(pout, plp, out);
}

// Round 9
// 472.575 us; speedup vs baseline: 1.1642x; 1.1642x over previous
//
#include <hip/hip_runtime.h>
#include <hip/hip_bf16.h>

#define NTOT 8192
#define DDIM 256
#define ROWS 32                 // rows per attn block
#define JWAVE 2048              // j per wave (jg = 0..3)
#define NITER (JWAVE / 32)      // 64 j-tiles per wave
#define NWORDS (NTOT / 32)      // 256 bitmask words per row
#define NTSTR 131584            // hTf nt-stride in elems: 257*64*8
#define HTF_ELEMS (16 * NTSTR)

typedef __attribute__((ext_vector_type(8))) short short8;
typedef __attribute__((ext_vector_type(4))) float floatx4;
typedef __attribute__((ext_vector_type(4))) int intx4;

static __device__ __forceinline__ short bfp(float f) {
  __hip_bfloat16 b = __float2bfloat16(f);
  return *(short*)&b;
}

// ------- per-row exp tables: rc=(e^s1, e^.01s1), etab=(e^s2, e^.01s2)
// exp(leaky(s1+s2)) = max(e^s1*e^s2, e^.01s1*e^.01s2)
__global__ __launch_bounds__(256) void gat_scores(const float* __restrict__ h,
                                                  const float* __restrict__ a,
                                                  float2* __restrict__ rc,
                                                  float2* __restrict__ etab) {
  int row  = blockIdx.x * 4 + (threadIdx.x >> 6);
  int lane = threadIdx.x & 63;
  const float* hr = h + (size_t)row * DDIM;
  float p1 = 0.f, p2 = 0.f;
#pragma unroll
  for (int k = 0; k < DDIM / 64; ++k) {
    int idx  = lane + 64 * k;
    float hv = hr[idx];
    p1 += hv * a[idx];
    p2 += hv * a[DDIM + idx];
  }
#pragma unroll
  for (int off = 32; off > 0; off >>= 1) {
    p1 += __shfl_down(p1, off, 64);
    p2 += __shfl_down(p2, off, 64);
  }
  if (lane == 0) {
    rc[row]   = make_float2(__expf(p1), __expf(0.01f * p1));
    etab[row] = make_float2(__expf(p2), __expf(0.01f * p2));
  }
}

// ---------------- pack adj -> word-major bitmask bitsT[jw][row] -------------
// (verified in R0) Coalesced mask reads in attn: 1 word covers 32 j of a row.
__global__ __launch_bounds__(256) void gat_pack(const int* __restrict__ adj,
                                                unsigned* __restrict__ bitsT) {
  __shared__ unsigned words[64][65];
  const int t    = threadIdx.x;
  const int lane = t & 63;
  const int w    = t >> 6;
  const int r0   = blockIdx.x * 64;
  const int jb   = blockIdx.y * 2048;

#pragma unroll 2
  for (int rr = 0; rr < 16; ++rr) {
    const int rl = w * 16 + rr;
    const int* ap = adj + (size_t)(r0 + rl) * NTOT + jb + lane * 4;
#pragma unroll
    for (int R = 0; R < 8; ++R) {
      intx4 v = __builtin_nontemporal_load((const intx4*)(ap + R * 256));
      unsigned nib = (v[0] > 0 ? 1u : 0u) | (v[1] > 0 ? 2u : 0u) |
                     (v[2] > 0 ? 4u : 0u) | (v[3] > 0 ? 8u : 0u);
      unsigned b8  = nib | (__shfl_xor((int)nib, 1, 64) << 4);
      unsigned b16 = b8  | (__shfl_xor((int)b8,  2, 64) << 8);
      unsigned b32 = b16 | (__shfl_xor((int)b16, 4, 64) << 16);
      if ((lane & 7) == 0) words[rl][R * 8 + (lane >> 3)] = b32;
    }
  }
  __syncthreads();

#pragma unroll 4
  for (int kk = 0; kk < 16; ++kk) {
    const int jwl = w * 16 + kk;
    bitsT[(size_t)(jb / 32 + jwl) * NTOT + r0 + lane] = words[lane][jwl];
  }
}

// ---------------- pack h -> fragment-major bf16 hTf (padded nt-stride) ------
__global__ __launch_bounds__(256) void gat_hpack(const float* __restrict__ h,
                                                 ushort* __restrict__ hTf) {
  __shared__ float tile[64][257];
  const int t    = threadIdx.x;
  const int lane = t & 63;
  const int w    = t >> 6;
  const int quad = lane >> 4;
  const int c    = lane & 15;
  const int i0   = blockIdx.x * 64;

#pragma unroll
  for (int it = 0; it < 16; ++it) {
    int r = it * 4 + w;
    float4 v = *(const float4*)(h + (size_t)(i0 + r) * DDIM + lane * 4);
    tile[r][lane * 4 + 0] = v.x; tile[r][lane * 4 + 1] = v.y;
    tile[r][lane * 4 + 2] = v.z; tile[r][lane * 4 + 3] = v.w;
  }
  __syncthreads();

#pragma unroll
  for (int k = 0; k < 4; ++k) {
    const int n = 4 * k + w;
#pragma unroll
    for (int jbl = 0; jbl < 2; ++jbl) {
      short8 vv;
#pragma unroll
      for (int i = 0; i < 8; ++i) {
        float f = tile[jbl * 32 + quad * 8 + i][n * 16 + c];
        vv[i] = bfp(f);
      }
      *(short8*)(hTf + ((size_t)(n * 257 + i0 / 32 + jbl) * 64 + lane) * 8) = vv;
    }
  }
}

// ---------------- barrier-free fused softmax + P@h via MFMA -----------------
// grid 256 x 1024 thr (16 waves) = 1 block/CU, 4 waves/SIMD (<=128 unified).
// Block: rows [32bx,+32) x all j. Wave (cg=w&3, jg=w>>2): 32 rows (2 A-frags,
// B-reuse=2), cols [64cg,+64) (4 B-frags), j [2048jg,+2048).
// Per-iter cache-line budget: hTf 64 + mask ~3 + etab ~8 (was 208 in R6 --
// the measured per-CU line-rate bound). Bitmask adj: 2 coalesced u32 loads.
__global__ __launch_bounds__(1024, 4) void gat_attn(const ushort* __restrict__ hTf,
                                                    const unsigned* __restrict__ bitsT,
                                                    const float2* __restrict__ rc,
                                                    const float2* __restrict__ etab,
                                                    float* __restrict__ out) {
  __shared__ float slab[8][32][64];   // jg merge buffers: 64 KB
  __shared__ float lsum[4][32];       // per-jg denom partials

  const int t    = threadIdx.x;
  const int lane = t & 63;
  const int w    = t >> 6;
  const int quad = lane >> 4;
  const int c    = lane & 15;
  const int cg   = w & 3;
  const int jg   = w >> 2;
  const int r0   = blockIdx.x * ROWS;
  const int j0   = jg * JWAVE;

  const float2 rc0 = rc[r0 + c];
  const float2 rc1 = rc[r0 + 16 + c];
  const float E10 = rc0.x, E20 = rc0.y;
  const float E11 = rc1.x, E21 = rc1.y;

  const unsigned* mb  = bitsT + (size_t)(j0 / 32) * NTOT + r0;
  const float*    etb = (const float*)(etab + j0 + quad * 8);
  const ushort*   hb  = hTf + (size_t)(cg * 4) * NTSTR + (size_t)(j0 / 32) * 512 + lane * 8;

  floatx4 acc[2][4];
#pragma unroll
  for (int rt = 0; rt < 2; ++rt)
#pragma unroll
    for (int q = 0; q < 4; ++q) acc[rt][q] = (floatx4){0.f, 0.f, 0.f, 0.f};

  float lp0 = 0.f, lp1 = 0.f;
  short8 bD[4];
  unsigned W0, W1;
  float4 ea, eb, ec, ed;

  #define LDM(jt)                                                              \
    {                                                                          \
      const unsigned* m_ = mb + (size_t)(jt) * NTOT;                           \
      W0 = m_[c];                                                              \
      W1 = m_[16 + c];                                                         \
    }
  #define LDE(jt)                                                              \
    {                                                                          \
      const float* e_ = etb + (size_t)(jt) * 64;                               \
      ea = ((const float4*)e_)[0];                                             \
      eb = ((const float4*)e_)[1];                                             \
      ec = ((const float4*)e_)[2];                                             \
      ed = ((const float4*)e_)[3];                                             \
    }
  #define LDB01(jt)                                                            \
    bD[0] = *(const short8*)(hb + (size_t)(jt) * 512);                         \
    bD[1] = *(const short8*)(hb + (size_t)(jt) * 512 + NTSTR);
  #define LDB23(jt)                                                            \
    bD[2] = *(const short8*)(hb + (size_t)(jt) * 512 + 2 * (size_t)NTSTR);     \
    bD[3] = *(const short8*)(hb + (size_t)(jt) * 512 + 3 * (size_t)NTSTR);

  // prologue
  LDB01(0)
  LDB23(0)
  LDM(0)
  LDE(0)

  for (int jt = 0; jt < NITER; ++jt) {
    const int jn = (jt + 1) & (NITER - 1);   // wrapped (branch-free)

    // ---- P-build: p = bit ? max(E1*t1, E2*t2) : 0 ----
    const unsigned bm0 = (W0 >> (quad * 8)) & 0xff;
    const unsigned bm1 = (W1 >> (quad * 8)) & 0xff;
    const float tp[16] = {ea.x, ea.y, ea.z, ea.w, eb.x, eb.y, eb.z, eb.w,
                          ec.x, ec.y, ec.z, ec.w, ed.x, ed.y, ed.z, ed.w};
    short8 pa0, pa1;
#pragma unroll
    for (int i = 0; i < 8; ++i) {
      const float t1 = tp[2 * i], t2 = tp[2 * i + 1];
      const float m  = fmaxf(E10 * t1, E20 * t2);
      const float n  = fmaxf(E11 * t1, E21 * t2);
      const float p0 = ((bm0 >> i) & 1u) ? m : 0.f;
      const float p1 = ((bm1 >> i) & 1u) ? n : 0.f;
      lp0 += p0; lp1 += p1;
      pa0[i] = bfp(p0);
      pa1[i] = bfp(p1);
    }

    // ---- prefetch next mask + etab; pin ----
    LDM(jn)
    LDE(jn)
    __builtin_amdgcn_sched_barrier(0);

    // ---- MFMA on bD[0..1] (each reused by both A-frags), refill, pin ----
    acc[0][0] = __builtin_amdgcn_mfma_f32_16x16x32_bf16(pa0, bD[0], acc[0][0], 0, 0, 0);
    acc[1][0] = __builtin_amdgcn_mfma_f32_16x16x32_bf16(pa1, bD[0], acc[1][0], 0, 0, 0);
    acc[0][1] = __builtin_amdgcn_mfma_f32_16x16x32_bf16(pa0, bD[1], acc[0][1], 0, 0, 0);
    acc[1][1] = __builtin_amdgcn_mfma_f32_16x16x32_bf16(pa1, bD[1], acc[1][1], 0, 0, 0);
    LDB01(jn)
    __builtin_amdgcn_sched_barrier(0);

    // ---- MFMA on bD[2..3], refill, pin ----
    acc[0][2] = __builtin_amdgcn_mfma_f32_16x16x32_bf16(pa0, bD[2], acc[0][2], 0, 0, 0);
    acc[1][2] = __builtin_amdgcn_mfma_f32_16x16x32_bf16(pa1, bD[2], acc[1][2], 0, 0, 0);
    acc[0][3] = __builtin_amdgcn_mfma_f32_16x16x32_bf16(pa0, bD[3], acc[0][3], 0, 0, 0);
    acc[1][3] = __builtin_amdgcn_mfma_f32_16x16x32_bf16(pa1, bD[3], acc[1][3], 0, 0, 0);
    LDB23(jn)
    __builtin_amdgcn_sched_barrier(0);
  }
  #undef LDM
  #undef LDE
  #undef LDB01
  #undef LDB23

  // ---- denom: fold quads; every lane holds its rows' sums over wave's j ----
  lp0 += __shfl_xor(lp0, 16, 64); lp0 += __shfl_xor(lp0, 32, 64);
  lp1 += __shfl_xor(lp1, 16, 64); lp1 += __shfl_xor(lp1, 32, 64);
  if (cg == 0 && lane < 16) { lsum[jg][lane] = lp0; lsum[jg][16 + lane] = lp1; }

  // ---- jg-tree merge: 4 -> 2 -> 1 (per cg, 32 rows x 64 cols) ----
  if (jg >= 2) {
#pragma unroll
    for (int rt = 0; rt < 2; ++rt)
#pragma unroll
      for (int q = 0; q < 4; ++q)
#pragma unroll
        for (int r = 0; r < 4; ++r)
          slab[(jg - 2) * 4 + cg][rt * 16 + quad * 4 + r][q * 16 + c] = acc[rt][q][r];
  }
  __syncthreads();
  if (jg < 2) {
#pragma unroll
    for (int rt = 0; rt < 2; ++rt)
#pragma unroll
      for (int q = 0; q < 4; ++q)
#pragma unroll
        for (int r = 0; r < 4; ++r)
          acc[rt][q][r] += slab[jg * 4 + cg][rt * 16 + quad * 4 + r][q * 16 + c];
  }
  __syncthreads();
  if (jg == 1) {
#pragma unroll
    for (int rt = 0; rt < 2; ++rt)
#pragma unroll
      for (int q = 0; q < 4; ++q)
#pragma unroll
        for (int r = 0; r < 4; ++r)
          slab[cg][rt * 16 + quad * 4 + r][q * 16 + c] = acc[rt][q][r];
  }
  __syncthreads();
  if (jg == 0) {
    float linv[2][4];
#pragma unroll
    for (int rt = 0; rt < 2; ++rt)
#pragma unroll
      for (int r = 0; r < 4; ++r) {
        const int lr = rt * 16 + quad * 4 + r;
        linv[rt][r] = 1.f / (lsum[0][lr] + lsum[1][lr] + lsum[2][lr] + lsum[3][lr]);
      }
#pragma unroll
    for (int rt = 0; rt < 2; ++rt)
#pragma unroll
      for (int q = 0; q < 4; ++q)
#pragma unroll
        for (int r = 0; r < 4; ++r) {
          float v = acc[rt][q][r] + slab[cg][rt * 16 + quad * 4 + r][q * 16 + c];
          __builtin_nontemporal_store(
              v * linv[rt][r],
              &out[(size_t)(r0 + rt * 16 + quad * 4 + r) * DDIM +
                   (cg * 4 + q) * 16 + c]);
        }
  }
}

extern "C" void kernel_launch(void* const* d_in, const int* in_sizes, int n_in,
                              void* d_out, int out_size, void* d_ws, size_t ws_size,
                              hipStream_t stream) {
  const float* h   = (const float*)d_in[0];
  const int*   adj = (const int*)d_in[1];
  const float* a   = (const float*)d_in[2];
  float* out = (float*)d_out;

  float2*   rc    = (float2*)d_ws;                       // 8192 float2 = 64 KB
  float2*   etab  = rc + NTOT;                           // 8192 float2 = 64 KB
  unsigned* bitsT = (unsigned*)(etab + NTOT);            // 256*8192 u32 = 8 MB
  ushort*   hTf   = (ushort*)(bitsT + (size_t)NWORDS * NTOT);  // 4.21 MB bf16

  gat_scores<<<NTOT / 4, 256, 0, stream>>>(h, a, rc, etab);
  gat_pack<<<dim3(NTOT / 64, 4), 256, 0, stream>>>(adj, bitsT);
  gat_hpack<<<NTOT / 64, 256, 0, stream>>>(h, hTf);
  gat_attn<<<NTOT / ROWS, 1024, 0, stream>>>(hTf, bitsT, rc, etab, out);
}

// Round 10
// 455.831 us; speedup vs baseline: 1.2070x; 1.0367x over previous
//
#include <hip/hip_runtime.h>
#include <hip/hip_bf16.h>

#define NTOT 8192
#define DDIM 256
#define ROWS 64                 // rows per attn block (B-reuse = 4 A-frags)
#define JSPL 2                  // j-split across blocks (partials + combine)
#define JBLK (NTOT / JSPL)      // 4096 j per block
#define JWAVE (JBLK / 4)        // 1024 j per wave (jg = 0..3)
#define NITER (JWAVE / 32)      // 32 j-tiles per wave
#define NTSTR 131584            // hTf nt-stride in elems: 257*64*8
#define HTF_ELEMS (16 * NTSTR)

typedef __attribute__((ext_vector_type(8))) short short8;
typedef __attribute__((ext_vector_type(4))) float floatx4;
typedef __attribute__((ext_vector_type(4))) int intx4;

static __device__ __forceinline__ short bfp(float f) {
  __hip_bfloat16 b = __float2bfloat16(f);
  return *(short*)&b;
}

// ------- per-row exp tables: rc=(e^s1, e^.01s1), etab=(e^s2, e^.01s2)
// exp(leaky(s1+s2)) = max(e^s1*e^s2, e^.01s1*e^.01s2)
__global__ __launch_bounds__(256) void gat_scores(const float* __restrict__ h,
                                                  const float* __restrict__ a,
                                                  float2* __restrict__ rc,
                                                  float2* __restrict__ etab) {
  int row  = blockIdx.x * 4 + (threadIdx.x >> 6);
  int lane = threadIdx.x & 63;
  const float* hr = h + (size_t)row * DDIM;
  float p1 = 0.f, p2 = 0.f;
#pragma unroll
  for (int k = 0; k < DDIM / 64; ++k) {
    int idx  = lane + 64 * k;
    float hv = hr[idx];
    p1 += hv * a[idx];
    p2 += hv * a[DDIM + idx];
  }
#pragma unroll
  for (int off = 32; off > 0; off >>= 1) {
    p1 += __shfl_down(p1, off, 64);
    p2 += __shfl_down(p2, off, 64);
  }
  if (lane == 0) {
    rc[row]   = make_float2(__expf(p1), __expf(0.01f * p1));
    etab[row] = make_float2(__expf(p2), __expf(0.01f * p2));
  }
}

// ---------------- pack h -> fragment-major bf16 hTf (padded nt-stride) ------
__global__ __launch_bounds__(256) void gat_hpack(const float* __restrict__ h,
                                                 ushort* __restrict__ hTf) {
  __shared__ float tile[64][257];
  const int t    = threadIdx.x;
  const int lane = t & 63;
  const int w    = t >> 6;
  const int quad = lane >> 4;
  const int c    = lane & 15;
  const int i0   = blockIdx.x * 64;

#pragma unroll
  for (int it = 0; it < 16; ++it) {
    int r = it * 4 + w;
    float4 v = *(const float4*)(h + (size_t)(i0 + r) * DDIM + lane * 4);
    tile[r][lane * 4 + 0] = v.x; tile[r][lane * 4 + 1] = v.y;
    tile[r][lane * 4 + 2] = v.z; tile[r][lane * 4 + 3] = v.w;
  }
  __syncthreads();

#pragma unroll
  for (int k = 0; k < 4; ++k) {
    const int n = 4 * k + w;
#pragma unroll
    for (int jbl = 0; jbl < 2; ++jbl) {
      short8 vv;
#pragma unroll
      for (int i = 0; i < 8; ++i) {
        float f = tile[jbl * 32 + quad * 8 + i][n * 16 + c];
        vv[i] = bfp(f);
      }
      *(short8*)(hTf + ((size_t)(n * 257 + i0 / 32 + jbl) * 64 + lane) * 8) = vv;
    }
  }
}

// ---------------- barrier-free fused softmax-num + P@h partials via MFMA ----
// grid (128, 2) x 512 thr (8 waves) = 1 block/CU, 2 waves/SIMD (~254 unified
// regs: acc[4][8]=128 AGPR + ~125 VGPR). Block (rt, jb): rows [64rt,+64),
// j [4096jb,+4096). Wave (cg=w&1, jg=w>>1): 64 rows (4 A-frags, B-REUSE=4),
// cols [128cg,+128) (8 B-frags), j [1024jg,+1024).
// hTf total re-read: 537 MB (R2: 1.07 GB) -- time tracked traffic in R2/R6/R9.
__global__ __launch_bounds__(512, 2) void gat_attn(const ushort* __restrict__ hTf,
                                                   const int* __restrict__ adj,
                                                   const float2* __restrict__ rc,
                                                   const float2* __restrict__ etab,
                                                   float* __restrict__ pout,
                                                   float* __restrict__ plp) {
  __shared__ float slab[4][64][64];   // jg merge buffers (per col-half): 64 KB
  __shared__ float lsum[4][64];       // per-jg denom partials

  const int t    = threadIdx.x;
  const int lane = t & 63;
  const int w    = t >> 6;
  const int quad = lane >> 4;
  const int c    = lane & 15;
  const int cg   = w & 1;
  const int jg   = w >> 1;
  const int r0   = blockIdx.x * ROWS;
  const int jb   = blockIdx.y;
  const int j0   = jb * JBLK + jg * JWAVE;

  const float2 rv0 = rc[r0 + c];
  const float2 rv1 = rc[r0 + 16 + c];
  const float2 rv2 = rc[r0 + 32 + c];
  const float2 rv3 = rc[r0 + 48 + c];

  const int* ap0 = adj + (size_t)(r0 + c) * NTOT + j0 + quad * 8;
  const int* ap1 = ap0 + (size_t)16 * NTOT;
  const int* ap2 = ap0 + (size_t)32 * NTOT;
  const int* ap3 = ap0 + (size_t)48 * NTOT;
  const float*  etb = (const float*)(etab + j0 + quad * 8);
  const ushort* hb  = hTf + (size_t)(cg * 8) * NTSTR + (size_t)(j0 / 32) * 512 + lane * 8;

  floatx4 acc[4][8];
#pragma unroll
  for (int f = 0; f < 4; ++f)
#pragma unroll
    for (int q = 0; q < 8; ++q) acc[f][q] = (floatx4){0.f, 0.f, 0.f, 0.f};

  float lp0 = 0.f, lp1 = 0.f, lp2 = 0.f, lp3 = 0.f;
  short8 bD[8];
  intx4 a0a, a0b, a1a, a1b, a2a, a2b, a3a, a3b;
  float4 ea, eb, ec, ed;

  #define LDA(jt)                                                              \
    a0a = __builtin_nontemporal_load((const intx4*)(ap0 + (size_t)(jt) * 32)); \
    a0b = __builtin_nontemporal_load((const intx4*)(ap0 + (size_t)(jt) * 32 + 4)); \
    a1a = __builtin_nontemporal_load((const intx4*)(ap1 + (size_t)(jt) * 32)); \
    a1b = __builtin_nontemporal_load((const intx4*)(ap1 + (size_t)(jt) * 32 + 4)); \
    a2a = __builtin_nontemporal_load((const intx4*)(ap2 + (size_t)(jt) * 32)); \
    a2b = __builtin_nontemporal_load((const intx4*)(ap2 + (size_t)(jt) * 32 + 4)); \
    a3a = __builtin_nontemporal_load((const intx4*)(ap3 + (size_t)(jt) * 32)); \
    a3b = __builtin_nontemporal_load((const intx4*)(ap3 + (size_t)(jt) * 32 + 4));
  #define LDE(jt)                                                              \
    {                                                                          \
      const float* e_ = etb + (size_t)(jt) * 64;                               \
      ea = ((const float4*)e_)[0];                                             \
      eb = ((const float4*)e_)[1];                                             \
      ec = ((const float4*)e_)[2];                                             \
      ed = ((const float4*)e_)[3];                                             \
    }
  #define LDB03(jt)                                                            \
    bD[0] = *(const short8*)(hb + (size_t)(jt) * 512);                         \
    bD[1] = *(const short8*)(hb + (size_t)(jt) * 512 + (size_t)1 * NTSTR);     \
    bD[2] = *(const short8*)(hb + (size_t)(jt) * 512 + (size_t)2 * NTSTR);     \
    bD[3] = *(const short8*)(hb + (size_t)(jt) * 512 + (size_t)3 * NTSTR);
  #define LDB47(jt)                                                            \
    bD[4] = *(const short8*)(hb + (size_t)(jt) * 512 + (size_t)4 * NTSTR);     \
    bD[5] = *(const short8*)(hb + (size_t)(jt) * 512 + (size_t)5 * NTSTR);     \
    bD[6] = *(const short8*)(hb + (size_t)(jt) * 512 + (size_t)6 * NTSTR);     \
    bD[7] = *(const short8*)(hb + (size_t)(jt) * 512 + (size_t)7 * NTSTR);

  // P-build for one A-frag: p = (adj>0) ? max(E1*t1, E2*t2) : 0
  #define PB(AA, AB, RV, PAF, LPF)                                             \
    {                                                                          \
      const int am[8] = {AA[0], AA[1], AA[2], AA[3], AB[0], AB[1], AB[2], AB[3]}; \
      _Pragma("unroll")                                                        \
      for (int i = 0; i < 8; ++i) {                                            \
        const float p = (am[i] > 0)                                            \
            ? fmaxf(RV.x * tp[2 * i], RV.y * tp[2 * i + 1]) : 0.f;             \
        LPF += p;                                                              \
        PAF[i] = bfp(p);                                                       \
      }                                                                        \
    }

  // prologue
  LDB03(0)
  LDB47(0)
  LDA(0)
  LDE(0)

  for (int jt = 0; jt < NITER; ++jt) {
    const int jn = (jt + 1) & (NITER - 1);   // wrapped (branch-free)

    const float tp[16] = {ea.x, ea.y, ea.z, ea.w, eb.x, eb.y, eb.z, eb.w,
                          ec.x, ec.y, ec.z, ec.w, ed.x, ed.y, ed.z, ed.w};
    short8 pa0, pa1, pa2, pa3;
    PB(a0a, a0b, rv0, pa0, lp0)
    PB(a1a, a1b, rv1, pa1, lp1)
    PB(a2a, a2b, rv2, pa2, lp2)
    PB(a3a, a3b, rv3, pa3, lp3)

    // ---- prefetch next adj + etab; pin ----
    LDA(jn)
    LDE(jn)
    __builtin_amdgcn_sched_barrier(0);

    // ---- MFMA col-frags 0-3 (each B reused by 4 A-frags), refill, pin ----
#pragma unroll
    for (int q = 0; q < 4; ++q) {
      acc[0][q] = __builtin_amdgcn_mfma_f32_16x16x32_bf16(pa0, bD[q], acc[0][q], 0, 0, 0);
      acc[1][q] = __builtin_amdgcn_mfma_f32_16x16x32_bf16(pa1, bD[q], acc[1][q], 0, 0, 0);
      acc[2][q] = __builtin_amdgcn_mfma_f32_16x16x32_bf16(pa2, bD[q], acc[2][q], 0, 0, 0);
      acc[3][q] = __builtin_amdgcn_mfma_f32_16x16x32_bf16(pa3, bD[q], acc[3][q], 0, 0, 0);
    }
    LDB03(jn)
    __builtin_amdgcn_sched_barrier(0);

    // ---- MFMA col-frags 4-7, refill, pin ----
#pragma unroll
    for (int q = 4; q < 8; ++q) {
      acc[0][q] = __builtin_amdgcn_mfma_f32_16x16x32_bf16(pa0, bD[q], acc[0][q], 0, 0, 0);
      acc[1][q] = __builtin_amdgcn_mfma_f32_16x16x32_bf16(pa1, bD[q], acc[1][q], 0, 0, 0);
      acc[2][q] = __builtin_amdgcn_mfma_f32_16x16x32_bf16(pa2, bD[q], acc[2][q], 0, 0, 0);
      acc[3][q] = __builtin_amdgcn_mfma_f32_16x16x32_bf16(pa3, bD[q], acc[3][q], 0, 0, 0);
    }
    LDB47(jn)
    __builtin_amdgcn_sched_barrier(0);
  }
  #undef LDA
  #undef LDE
  #undef LDB03
  #undef LDB47
  #undef PB

  // ---- denom: fold quads; lanes 0-15 hold row f*16+c sums for wave's j ----
  lp0 += __shfl_xor(lp0, 16, 64); lp0 += __shfl_xor(lp0, 32, 64);
  lp1 += __shfl_xor(lp1, 16, 64); lp1 += __shfl_xor(lp1, 32, 64);
  lp2 += __shfl_xor(lp2, 16, 64); lp2 += __shfl_xor(lp2, 32, 64);
  lp3 += __shfl_xor(lp3, 16, 64); lp3 += __shfl_xor(lp3, 32, 64);
  if (cg == 0 && lane < 16) {
    lsum[jg][lane]      = lp0;
    lsum[jg][16 + lane] = lp1;
    lsum[jg][32 + lane] = lp2;
    lsum[jg][48 + lane] = lp3;
  }

  // ---- jg-tree merge 4->2->1 per col-half hd (slab = 64 rows x 64 cols) ----
  float* pob = pout + (size_t)jb * NTOT * DDIM;
#pragma unroll
  for (int hd = 0; hd < 2; ++hd) {
    if (jg >= 2) {
#pragma unroll
      for (int f = 0; f < 4; ++f)
#pragma unroll
        for (int qq = 0; qq < 4; ++qq)
#pragma unroll
          for (int r = 0; r < 4; ++r)
            slab[(jg - 2) * 2 + cg][f * 16 + quad * 4 + r][qq * 16 + c] =
                acc[f][hd * 4 + qq][r];
    }
    __syncthreads();
    if (jg < 2) {
#pragma unroll
      for (int f = 0; f < 4; ++f)
#pragma unroll
        for (int qq = 0; qq < 4; ++qq)
#pragma unroll
          for (int r = 0; r < 4; ++r)
            acc[f][hd * 4 + qq][r] +=
                slab[jg * 2 + cg][f * 16 + quad * 4 + r][qq * 16 + c];
    }
    __syncthreads();
    if (jg == 1) {
#pragma unroll
      for (int f = 0; f < 4; ++f)
#pragma unroll
        for (int qq = 0; qq < 4; ++qq)
#pragma unroll
          for (int r = 0; r < 4; ++r)
            slab[cg][f * 16 + quad * 4 + r][qq * 16 + c] = acc[f][hd * 4 + qq][r];
    }
    __syncthreads();
    if (jg == 0) {
#pragma unroll
      for (int f = 0; f < 4; ++f)
#pragma unroll
        for (int qq = 0; qq < 4; ++qq)
#pragma unroll
          for (int r = 0; r < 4; ++r) {
            float v = acc[f][hd * 4 + qq][r] +
                      slab[cg][f * 16 + quad * 4 + r][qq * 16 + c];
            __builtin_nontemporal_store(
                v, &pob[(size_t)(r0 + f * 16 + quad * 4 + r) * DDIM +
                        cg * 128 + hd * 64 + qq * 16 + c]);
          }
    }
    __syncthreads();
  }

  // ---- partial denominators for this j-half ----
  if (jg == 0 && cg == 0 && lane < 16) {
#pragma unroll
    for (int f = 0; f < 4; ++f) {
      const int lr = f * 16 + lane;
      plp[(size_t)jb * NTOT + r0 + lr] =
          lsum[0][lr] + lsum[1][lr] + lsum[2][lr] + lsum[3][lr];
    }
  }
}

// ---------------- combine the 2 j-half partials, divide by denom ------------
__global__ __launch_bounds__(256) void gat_combine(const float* __restrict__ pout,
                                                   const float* __restrict__ plp,
                                                   float* __restrict__ out) {
  const int idx = blockIdx.x * 256 + threadIdx.x;   // float4-group index
  const int row = idx >> 6;                          // 64 float4 per row
  float4 a = ((const float4*)pout)[idx];
  float4 b = ((const float4*)(pout + (size_t)NTOT * DDIM))[idx];
  float inv = 1.f / (plp[row] + plp[NTOT + row]);
  float4 r;
  r.x = (a.x + b.x) * inv;
  r.y = (a.y + b.y) * inv;
  r.z = (a.z + b.z) * inv;
  r.w = (a.w + b.w) * inv;
  __builtin_nontemporal_store(r.x, &out[idx * 4 + 0]);
  __builtin_nontemporal_store(r.y, &out[idx * 4 + 1]);
  __builtin_nontemporal_store(r.z, &out[idx * 4 + 2]);
  __builtin_nontemporal_store(r.w, &out[idx * 4 + 3]);
}

extern "C" void kernel_launch(void* const* d_in, const int* in_sizes, int n_in,
                              void* d_out, int out_size, void* d_ws, size_t ws_size,
                              hipStream_t stream) {
  const float* h   = (const float*)d_in[0];
  const int*   adj = (const int*)d_in[1];
  const float* a   = (const float*)d_in[2];
  float* out = (float*)d_out;

  float2*   rc    = (float2*)d_ws;                       // 8192 float2 = 64 KB
  float2*   etab  = rc + NTOT;                           // 8192 float2 = 64 KB
  ushort*   hTf   = (ushort*)(etab + NTOT);              // 4.21 MB bf16
  float*    pout  = (float*)(hTf + HTF_ELEMS);           // 2 x 8192 x 256 f32 = 16 MB
  float*    plp   = pout + (size_t)JSPL * NTOT * DDIM;   // 2 x 8192 f32

  gat_scores<<<NTOT / 4, 256, 0, stream>>>(h, a, rc, etab);
  gat_hpack<<<NTOT / 64, 256, 0, stream>>>(h, hTf);
  gat_attn<<<dim3(NTOT / ROWS, JSPL), 512, 0, stream>>>(hTf, adj, rc, etab, pout, plp);
  gat_combine<<<(NTOT * DDIM / 4) / 256, 256, 0, stream>>>(pout, plp, out);
}